// Round 7
// baseline (516.889 us; speedup 1.0000x reference)
//
#include <hip/hip_runtime.h>
#include <stdint.h>

// ---------- types ----------
typedef unsigned short bf16_t;
typedef __attribute__((ext_vector_type(8))) short   short8;   // 8 bf16 = 4 VGPRs (MFMA A/B frag)
typedef __attribute__((ext_vector_type(4))) float   floatx4;  // MFMA C/D frag
typedef __attribute__((ext_vector_type(4))) unsigned int   uint4v;
typedef __attribute__((ext_vector_type(4))) unsigned short ushort4v;

#define GAS __attribute__((address_space(1)))
#define LAS __attribute__((address_space(3)))

__device__ __forceinline__ unsigned short f2bf(float f) {
  unsigned u = __float_as_uint(f);
  u += 0x7FFFu + ((u >> 16) & 1u);   // RNE
  return (unsigned short)(u >> 16);
}

__device__ __forceinline__ void g2l16(const bf16_t* g, bf16_t* l) {
  // async global->LDS, 16B/lane; LDS dest is wave-uniform base + lane*16
  __builtin_amdgcn_global_load_lds((const GAS uint32_t*)g, (LAS uint32_t*)l, 16, 0, 0);
}

#define SB0() __builtin_amdgcn_sched_barrier(0)
// Unfenced barrier (no compiler memory clobber -> no forced vmcnt(0) drain),
// pinned on both sides so the machine scheduler can't move memory ops across.
#define BARX() do { SB0(); __builtin_amdgcn_s_barrier(); SB0(); } while (0)

// ---------- fp32 -> bf16 converts ----------
__global__ __launch_bounds__(256) void conv_f32_bf16(const float* __restrict__ s,
                                                     bf16_t* __restrict__ d) {
  size_t i = ((size_t)blockIdx.x * 256 + threadIdx.x) * 4;
  float4 v = *(const float4*)(s + i);
  ushort4v o = { f2bf(v.x), f2bf(v.y), f2bf(v.z), f2bf(v.w) };
  *(ushort4v*)(d + i) = o;
}

__global__ __launch_bounds__(256) void conv_w(const float* __restrict__ w0, const float* __restrict__ w1,
                                              const float* __restrict__ w2, const float* __restrict__ w3,
                                              bf16_t* __restrict__ d) {
  const float* s = blockIdx.y == 0 ? w0 : blockIdx.y == 1 ? w1 : blockIdx.y == 2 ? w2 : w3;
  size_t i = ((size_t)blockIdx.x * 256 + threadIdx.x) * 4;
  float4 v = *(const float4*)(s + i);
  ushort4v o = { f2bf(v.x), f2bf(v.y), f2bf(v.z), f2bf(v.w) };
  *(ushort4v*)(d + (size_t)blockIdx.y * 1048576 + i) = o;
}

// ---------- GEMM: C[M,N] = A[M,K] * B[N,K]^T (+bias) * scale ----------
// 256x256 tile, BK=64, 8 waves (2M x 4N), 512 threads, 128 KB LDS.
// R6/R7: 4-phase counted-vmcnt pipeline (T3+T4+T5), STRICT tile-level buffer
// alternation (the R3 race was same-buffer mid-tile restaging; eliminated).
// Per K-tile t (buf cur holds t; ALL tile-t stages target cur^1):
//   P1: reads k0/mh0 | STG A(t+1).k0          | bar | lgkm0 | 16 MFMA | bar
//   P2: reads k0/mh1 | STG B(t+1).k0 | GATE vmcnt(4) bar | lgkm0 | MFMA | bar
//   P3: reads k1/mh0 | STG A(t+1).k1          | bar | lgkm0 | 16 MFMA | bar
//   P4: reads k1/mh1 | STG B(t+1).k1 | MFMA | GATE vmcnt(4) | bar
// Per-wave load ledger (2 loads/STG): after prologue vmcnt(4), outstanding =
// own-tile k1 (4). P2-gate vmcnt(4) retires them (needed by P3); P4-gate
// vmcnt(4) retires next tile's k0 (needed by next P1). Last tile: P2 gate is
// vmcnt(0). Gates precede a barrier -> retirement is collective.
// Safety: no wave writes buf cur during tile t (strict alternation); every
// fragment read is consumed by MFMA in its own phase (cannot sink past use);
// lgkmcnt(0)+sched_barrier(0) before MFMA per rule #18.
template <typename OutT>
__global__ __launch_bounds__(512, 2) void gemm256(
    const bf16_t* __restrict__ A, const bf16_t* __restrict__ B,
    const float* __restrict__ bias, OutT* __restrict__ C,
    int M, int N, int K, long aBat, long bBat, long cBat, float scale)
{
  const int tid  = threadIdx.x;
  const int lane = tid & 63;
  const int wv   = tid >> 6;

  // bijective XCD swizzle (m204, r=0 case; all launches have nwg%8==0)
  int bx, by, bz;
  {
    const int gx = gridDim.x, gy = gridDim.y, gz = gridDim.z;
    const int nwg = gx * gy * gz;
    int flat = (blockIdx.z * gy + blockIdx.y) * gx + blockIdx.x;
    if ((nwg & 7) == 0) {
      const int q = nwg >> 3;
      flat = (flat & 7) * q + (flat >> 3);
    }
    bx = flat % gx;
    const int rem = flat / gx;
    by = rem % gy;
    bz = rem / gy;
  }
  const int bm = by * 256;
  const int bn = bx * 256;
  A += (size_t)bz * aBat;
  B += (size_t)bz * bBat;
  C += (size_t)bz * cBat;

  __shared__ bf16_t sm[65536];   // 128 KB: A[2][2][8192] then B[2][2][8192]

  const int nt = K >> 6;

  // wave -> 128x64 C sub-tile
  const int wm = (wv >> 2) * 128;
  const int wn = (wv & 3) * 64;

  // fragment addressing (R5-verified): regions are [256 rows][32 k-elems],
  // 16B chunk slot = kq ^ ((row>>1)&3), per-lane constant for 16-row frags.
  const int fr = lane & 15;
  const int kq = lane >> 4;
  const int chE = kq ^ ((fr >> 1) & 3);
  const unsigned fA = (unsigned)((wm + fr) * 32 + chE * 8);
  const unsigned fB = (unsigned)((wn + fr) * 32 + chE * 8);

  // staging addressing (R5-verified): LDS linear chunk i -> global chunk
  // (i&3)^((i>>3)&3); g2l16 dest stays linear (rule 21).
  const unsigned c0    = (unsigned)((tid & 3) ^ ((tid >> 3) & 3));
  const unsigned soff  = (unsigned)((tid >> 2) * K + c0 * 8);
  const unsigned kx128 = (unsigned)(K << 7);           // 128*K elems
  const unsigned lOff  = (unsigned)(wv * 512 + lane * 8);

  const bf16_t* gA = A + (size_t)bm * K;
  const bf16_t* gB = B + (size_t)bn * K;

#define SMA(b, kh) (sm + (((b) << 1) | (kh)) * 8192)
#define SMB(b, kh) (sm + 32768 + (((b) << 1) | (kh)) * 8192)
#define STG(gbase, lbase)                                   \
  do {                                                      \
    g2l16((gbase) + soff,         (lbase) + lOff);          \
    g2l16((gbase) + soff + kx128, (lbase) + lOff + 4096);   \
  } while (0)

  floatx4 acc[8][4];
  floatx4 zero = {0.0f, 0.0f, 0.0f, 0.0f};
#pragma unroll
  for (int i = 0; i < 8; i++)
#pragma unroll
    for (int j = 0; j < 4; j++) acc[i][j] = zero;

  // ---- prologue: stage tile 0 fully; retire its k0 units; barrier ----
  STG(gA,      SMA(0, 0));
  STG(gB,      SMB(0, 0));
  STG(gA + 32, SMA(0, 1));
  STG(gB + 32, SMB(0, 1));
  SB0();
  asm volatile("s_waitcnt vmcnt(4)");
  BARX();   // all waves' k0 visible; per-wave outstanding = own k1 (4 loads)

  int cur = 0;
  for (int t = 0; t < nt; ++t) {
    const int kc = t << 6;
    const bool pf = (t + 1 < nt);
    const bf16_t* Ac0 = SMA(cur, 0);
    const bf16_t* Ac1 = SMA(cur, 1);
    const bf16_t* Bc0 = SMB(cur, 0);
    const bf16_t* Bc1 = SMB(cur, 1);
    short8 a_[4], b_[4];

    // ===== P1: k0, m-half 0 | STG A(t+1).k0 -> cur^1 =====
#pragma unroll
    for (int i = 0; i < 4; i++) a_[i] = *(const short8*)(Ac0 + fA + i * 512);
#pragma unroll
    for (int i = 0; i < 4; i++) b_[i] = *(const short8*)(Bc0 + fB + i * 512);
    if (pf) STG(gA + kc + 64, SMA(cur ^ 1, 0));
    BARX();
    asm volatile("s_waitcnt lgkmcnt(0)");
    SB0();
    __builtin_amdgcn_s_setprio(1);
#pragma unroll
    for (int mi = 0; mi < 4; mi++)
#pragma unroll
      for (int ni = 0; ni < 4; ni++)
        acc[mi][ni] = __builtin_amdgcn_mfma_f32_16x16x32_bf16(a_[mi], b_[ni], acc[mi][ni], 0, 0, 0);
    __builtin_amdgcn_s_setprio(0);
    BARX();

    // ===== P2: k0, m-half 1 (B reused) | STG B(t+1).k0 | GATE =====
#pragma unroll
    for (int i = 0; i < 4; i++) a_[i] = *(const short8*)(Ac0 + fA + (4 + i) * 512);
    if (pf) STG(gB + kc + 64, SMB(cur ^ 1, 0));
    SB0();
    if (pf) asm volatile("s_waitcnt vmcnt(4)");   // retire this tile's k1 units
    else    asm volatile("s_waitcnt vmcnt(0)");
    BARX();
    asm volatile("s_waitcnt lgkmcnt(0)");
    SB0();
    __builtin_amdgcn_s_setprio(1);
#pragma unroll
    for (int mi = 0; mi < 4; mi++)
#pragma unroll
      for (int ni = 0; ni < 4; ni++)
        acc[4 + mi][ni] = __builtin_amdgcn_mfma_f32_16x16x32_bf16(a_[mi], b_[ni], acc[4 + mi][ni], 0, 0, 0);
    __builtin_amdgcn_s_setprio(0);
    BARX();

    // ===== P3: k1, m-half 0 | STG A(t+1).k1 -> cur^1 =====
#pragma unroll
    for (int i = 0; i < 4; i++) a_[i] = *(const short8*)(Ac1 + fA + i * 512);
#pragma unroll
    for (int i = 0; i < 4; i++) b_[i] = *(const short8*)(Bc1 + fB + i * 512);
    if (pf) STG(gA + kc + 96, SMA(cur ^ 1, 1));
    BARX();
    asm volatile("s_waitcnt lgkmcnt(0)");
    SB0();
    __builtin_amdgcn_s_setprio(1);
#pragma unroll
    for (int mi = 0; mi < 4; mi++)
#pragma unroll
      for (int ni = 0; ni < 4; ni++)
        acc[mi][ni] = __builtin_amdgcn_mfma_f32_16x16x32_bf16(a_[mi], b_[ni], acc[mi][ni], 0, 0, 0);
    __builtin_amdgcn_s_setprio(0);
    BARX();

    // ===== P4: k1, m-half 1 (B reused) | STG B(t+1).k1 | GATE =====
#pragma unroll
    for (int i = 0; i < 4; i++) a_[i] = *(const short8*)(Ac1 + fA + (4 + i) * 512);
    if (pf) STG(gB + kc + 96, SMB(cur ^ 1, 1));
    BARX();
    asm volatile("s_waitcnt lgkmcnt(0)");
    SB0();
    __builtin_amdgcn_s_setprio(1);
#pragma unroll
    for (int mi = 0; mi < 4; mi++)
#pragma unroll
      for (int ni = 0; ni < 4; ni++)
        acc[4 + mi][ni] = __builtin_amdgcn_mfma_f32_16x16x32_bf16(a_[mi], b_[ni], acc[4 + mi][ni], 0, 0, 0);
    __builtin_amdgcn_s_setprio(0);
    SB0();
    if (pf) asm volatile("s_waitcnt vmcnt(4)");   // retire next tile's k0 units
    BARX();

    cur ^= 1;
  }
#undef STG
#undef SMB
#undef SMA

  // full drain before LDS reuse (also covers last-tile residuals)
  __syncthreads();

  // ---- epilogue: LDS-staged, full-line stores (R2/R5-verified bytes) ----
  {
    const int er = (lane >> 4) * 4;
    const int ec = lane & 15;
    char* wreg = (char*)sm + wv * 16384;   // per-wave private staging
#pragma unroll
    for (int pass = 0; pass < 2; ++pass) {
#pragma unroll
      for (int nf = 0; nf < 4; nf++) {
        const int lcol = nf * 16 + ec;                 // 0..63
        const float bval = bias ? bias[bn + wn + lcol] : 0.0f;
#pragma unroll
        for (int mh = 0; mh < 4; mh++) {
#pragma unroll
          for (int r = 0; r < 4; r++) {
            float v = (acc[pass * 4 + mh][nf][r] + bval) * scale;
            const int row = mh * 16 + er + r;          // 0..63
            if constexpr (sizeof(OutT) == 4) {
              ((float*)wreg)[row * 64 + lcol] = v;
            } else {
              ((bf16_t*)wreg)[row * 64 + lcol] = f2bf(v);
            }
          }
        }
      }
      const size_t rbase = (size_t)(bm + wm + pass * 64);
      if constexpr (sizeof(OutT) == 4) {
        const float* tf = (const float*)wreg;          // 64 x 256B rows
        float* Cf = (float*)C;
#pragma unroll
        for (int i = 0; i < 16; i++) {
          const int rr = i * 4 + (lane >> 4);
          floatx4 v = *(const floatx4*)(tf + rr * 64 + (lane & 15) * 4);
          *(floatx4*)(Cf + (rbase + rr) * N + bn + wn + (lane & 15) * 4) = v;
        }
      } else {
        const bf16_t* tb = (const bf16_t*)wreg;        // 64 x 128B rows
        bf16_t* Cb = (bf16_t*)C;
#pragma unroll
        for (int i = 0; i < 8; i++) {
          const int rr = i * 8 + (lane >> 3);
          short8 v = *(const short8*)(tb + rr * 64 + (lane & 7) * 8);
          *(short8*)(Cb + (rbase + rr) * N + bn + wn + (lane & 7) * 8) = v;
        }
      }
    }
  }
}

// ---------- row softmax in place, bf16 [16384][2048], one block per row ----------
__global__ __launch_bounds__(256) void softmax_rows(bf16_t* __restrict__ S) {
  const int tid = threadIdx.x;
  bf16_t* row = S + (size_t)blockIdx.x * 2048;
  uint4v raw = *(const uint4v*)(row + tid * 8);
  float x[8];
#pragma unroll
  for (int j = 0; j < 4; j++) {
    unsigned w = raw[j];
    x[2 * j]     = __uint_as_float(w << 16);
    x[2 * j + 1] = __uint_as_float(w & 0xFFFF0000u);
  }
  float m = -1e30f;
#pragma unroll
  for (int j = 0; j < 8; j++) m = fmaxf(m, x[j]);
  for (int o = 32; o > 0; o >>= 1) m = fmaxf(m, __shfl_xor(m, o, 64));
  __shared__ float red[4];
  if ((tid & 63) == 0) red[tid >> 6] = m;
  __syncthreads();
  m = fmaxf(fmaxf(red[0], red[1]), fmaxf(red[2], red[3]));

  float e[8];
  float s = 0.0f;
#pragma unroll
  for (int j = 0; j < 8; j++) { e[j] = __expf(x[j] - m); s += e[j]; }
  for (int o = 32; o > 0; o >>= 1) s += __shfl_xor(s, o, 64);
  __syncthreads();
  if ((tid & 63) == 0) red[tid >> 6] = s;
  __syncthreads();
  s = red[0] + red[1] + red[2] + red[3];
  float inv = 1.0f / s;

  uint4v o4;
#pragma unroll
  for (int j = 0; j < 4; j++) {
    unsigned lo = f2bf(e[2 * j] * inv);
    unsigned hi = f2bf(e[2 * j + 1] * inv);
    o4[j] = lo | (hi << 16);
  }
  *(uint4v*)(row + tid * 8) = o4;
}

// ---------- V [b][2048][1024] -> Vt [b][1024][2048], 64x64 LDS tiles ----------
__global__ __launch_bounds__(256) void transpose64(const bf16_t* __restrict__ V,
                                                   bf16_t* __restrict__ Vt) {
  __shared__ bf16_t t[64][72];   // 72: keep 16B alignment (144B row) + conflict break
  const int tid = threadIdx.x;
  const int e0 = blockIdx.x * 64;
  const int s0 = blockIdx.y * 64;
  const size_t bb = (size_t)blockIdx.z * (2048 * 1024);
  const int r = tid >> 2;
  const int c = (tid & 3) * 16;
  const bf16_t* src = V + bb + (size_t)(s0 + r) * 1024 + e0 + c;
  uint4v v0 = *(const uint4v*)src;
  uint4v v1 = *(const uint4v*)(src + 8);
  *(uint4v*)&t[r][c]     = v0;
  *(uint4v*)&t[r][c + 8] = v1;
  __syncthreads();
  __attribute__((aligned(16))) bf16_t vals[16];
#pragma unroll
  for (int j = 0; j < 16; j++) vals[j] = t[c + j][r];
  bf16_t* dst = Vt + bb + (size_t)(e0 + r) * 2048 + s0 + c;
  *(uint4v*)dst       = *(const uint4v*)vals;
  *(uint4v*)(dst + 8) = *(const uint4v*)(vals + 8);
}

// ---------- launch ----------
extern "C" void kernel_launch(void* const* d_in, const int* in_sizes, int n_in,
                              void* d_out, int out_size, void* d_ws, size_t ws_size,
                              hipStream_t stream) {
  const float* target = (const float*)d_in[0];
  const float* source = (const float*)d_in[1];
  const float* Wq = (const float*)d_in[2];
  const float* bq = (const float*)d_in[3];
  const float* Wk = (const float*)d_in[4];
  const float* bk = (const float*)d_in[5];
  const float* Wv = (const float*)d_in[6];
  const float* bv = (const float*)d_in[7];
  const float* Wo = (const float*)d_in[8];
  const float* bo = (const float*)d_in[9];
  float* out = (float*)d_out;

  // workspace layout (200 MB total), with overlays:
  //   [0,32M)      Q bf16
  //   [32M,64M)    K bf16
  //   [64M,96M)    V^T bf16
  //   [96M,104M)   Wq/Wk/Wv/Wo bf16
  //   [104M,136M)  target bf16  } S bf16 (64M) overlays both after QKV GEMMs
  //   [136M,168M)  source bf16  }
  //   [168M,200M)  V row-major bf16; attn-out overlays after transpose
  char* ws = (char*)d_ws;
  bf16_t* Qb  = (bf16_t*)(ws + 0);
  bf16_t* Kb  = (bf16_t*)(ws + 33554432);
  bf16_t* Vt  = (bf16_t*)(ws + 67108864);
  bf16_t* Wb  = (bf16_t*)(ws + 100663296);
  bf16_t* Tb  = (bf16_t*)(ws + 109051904);
  bf16_t* Sb  = Tb;                          // 67,108,864 B spanning Tb+Srcb
  bf16_t* Srb = (bf16_t*)(ws + 142606336);
  bf16_t* Vb  = (bf16_t*)(ws + 176160768);
  bf16_t* AO  = Vb;

  // 1. converts (fp32 -> bf16)
  conv_f32_bf16<<<16384, 256, 0, stream>>>(target, Tb);
  conv_f32_bf16<<<16384, 256, 0, stream>>>(source, Srb);
  conv_w<<<dim3(1024, 4), 256, 0, stream>>>(Wq, Wk, Wv, Wo, Wb);

  // 2. projections: X @ W^T + b   (Q pre-scaled by 1/sqrt(1024))
  gemm256<<<dim3(4, 64, 1), 512, 0, stream>>>(Tb,  Wb,           bq, Qb, 16384, 1024, 1024, 0L, 0L, 0L, 0.03125f);
  gemm256<<<dim3(4, 64, 1), 512, 0, stream>>>(Srb, Wb + 1048576, bk, Kb, 16384, 1024, 1024, 0L, 0L, 0L, 1.0f);
  gemm256<<<dim3(4, 64, 1), 512, 0, stream>>>(Srb, Wb + 2097152, bv, Vb, 16384, 1024, 1024, 0L, 0L, 0L, 1.0f);

  // 3. V -> V^T per batch
  transpose64<<<dim3(16, 32, 8), 256, 0, stream>>>(Vb, Vt);

  // 4. scores S = Qs @ K^T  (per batch)
  gemm256<<<dim3(8, 8, 8), 512, 0, stream>>>(Qb, Kb, (const float*)nullptr, Sb,
      2048, 2048, 1024, (long)2048 * 1024, (long)2048 * 1024, (long)2048 * 2048, 1.0f);

  // 5. softmax rows, in place
  softmax_rows<<<16384, 256, 0, stream>>>(Sb);

  // 6. out = P @ V  == P @ (V^T)^T  (per batch)
  gemm256<<<dim3(4, 8, 8), 512, 0, stream>>>(Sb, Vt, (const float*)nullptr, AO,
      2048, 1024, 2048, (long)2048 * 2048, (long)1024 * 2048, (long)2048 * 1024, 1.0f);

  // 7. final projection: AO @ Wo^T + bo -> fp32 out
  gemm256<<<dim3(4, 64, 1), 512, 0, stream>>>(AO, Wb + 3145728, bo, out,
      16384, 1024, 1024, 0L, 0L, 0L, 1.0f);
}

// Round 8
// 515.284 us; speedup vs baseline: 1.0031x; 1.0031x over previous
//
#include <hip/hip_runtime.h>
#include <stdint.h>

// ---------- types ----------
typedef unsigned short bf16_t;
typedef __attribute__((ext_vector_type(8))) short   short8;   // 8 bf16 = 4 VGPRs (MFMA A/B frag)
typedef __attribute__((ext_vector_type(4))) float   floatx4;  // MFMA C/D frag
typedef __attribute__((ext_vector_type(4))) unsigned int   uint4v;
typedef __attribute__((ext_vector_type(4))) unsigned short ushort4v;

#define GAS __attribute__((address_space(1)))
#define LAS __attribute__((address_space(3)))

__device__ __forceinline__ unsigned short f2bf(float f) {
  unsigned u = __float_as_uint(f);
  u += 0x7FFFu + ((u >> 16) & 1u);   // RNE
  return (unsigned short)(u >> 16);
}

__device__ __forceinline__ void g2l16(const bf16_t* g, bf16_t* l) {
  // async global->LDS, 16B/lane; LDS dest is wave-uniform base + lane*16
  __builtin_amdgcn_global_load_lds((const GAS uint32_t*)g, (LAS uint32_t*)l, 16, 0, 0);
}

#define SB0() __builtin_amdgcn_sched_barrier(0)

// ---------- fp32 -> bf16 converts (fused: target + source in one dispatch) ----------
__global__ __launch_bounds__(256) void conv_in(const float* __restrict__ a, const float* __restrict__ b,
                                               bf16_t* __restrict__ da, bf16_t* __restrict__ db) {
  const float* s = blockIdx.y ? b : a;
  bf16_t*      d = blockIdx.y ? db : da;
  size_t i = ((size_t)blockIdx.x * 256 + threadIdx.x) * 4;
  float4 v = *(const float4*)(s + i);
  ushort4v o = { f2bf(v.x), f2bf(v.y), f2bf(v.z), f2bf(v.w) };
  *(ushort4v*)(d + i) = o;
}

__global__ __launch_bounds__(256) void conv_w(const float* __restrict__ w0, const float* __restrict__ w1,
                                              const float* __restrict__ w2, const float* __restrict__ w3,
                                              bf16_t* __restrict__ d) {
  const float* s = blockIdx.y == 0 ? w0 : blockIdx.y == 1 ? w1 : blockIdx.y == 2 ? w2 : w3;
  size_t i = ((size_t)blockIdx.x * 256 + threadIdx.x) * 4;
  float4 v = *(const float4*)(s + i);
  ushort4v o = { f2bf(v.x), f2bf(v.y), f2bf(v.z), f2bf(v.w) };
  *(ushort4v*)(d + (size_t)blockIdx.y * 1048576 + i) = o;
}

// ---------- GEMM: C[M,N] = A[M,K] * B[N,K]^T (+bias) * scale ----------
// R8: 128x128 tile, BK=64, 4 waves (2M x 2N), 256 threads, 64 KB LDS
// double-buffered -> 2 BLOCKS/CU (LDS-limited; regs ~154 -> 3 waves/SIMD).
// Rationale: R5's 256²/1-block/CU kernel stalls ~9k cyc/tile at its per-tile
// drain with NOTHING else resident on the CU. Evidence: the same kernel runs
// ~2.6x faster on L2-hot QK^T/PV operands -> the stall is cold-staging
// latency exposed serially. 2 blocks/CU restores the m114 inter-block
// overlap (block B issues MFMA while block A drains) that made the m97-era
// 128² kernels fast, PLUS intra-block prefetch (stage-next-FIRST) that R0
// lacked. Loop structure is the R5-verified minimal 2-phase: stage next tile
// -> all ds_reads + 32 MFMAs -> ONE __syncthreads per K-tile (its
// vmcnt(0)+lgkmcnt(0) drain IS the sync; no inline-asm ordering games).
template <typename OutT>
__global__ __launch_bounds__(256, 2) void gemm128(
    const bf16_t* __restrict__ A, const bf16_t* __restrict__ B,
    const float* __restrict__ bias, OutT* __restrict__ C,
    int M, int N, int K, long aBat, long bBat, long cBat, float scale)
{
  const int tid  = threadIdx.x;
  const int lane = tid & 63;
  const int wv   = tid >> 6;          // 0..3

  // bijective XCD swizzle (m204, r=0 case; all launches have nwg%8==0):
  // each XCD gets a contiguous flat-id chunk -> neighboring tiles (sharing
  // A-row panels / B-col panels) colocate on one XCD's L2.
  int bx, by, bz;
  {
    const int gx = gridDim.x, gy = gridDim.y, gz = gridDim.z;
    const int nwg = gx * gy * gz;
    int flat = (blockIdx.z * gy + blockIdx.y) * gx + blockIdx.x;
    if ((nwg & 7) == 0) {
      const int q = nwg >> 3;
      flat = (flat & 7) * q + (flat >> 3);
    }
    bx = flat % gx;
    const int rem = flat / gx;
    by = rem % gy;
    bz = rem / gy;
  }
  const int bm = by * 128;
  const int bn = bx * 128;
  A += (size_t)bz * aBat;
  B += (size_t)bz * bBat;
  C += (size_t)bz * cBat;

  __shared__ bf16_t sm[32768];   // 64 KB: A[2buf][2kh][4096] then B likewise

  const int nt = K >> 6;

  // wave -> 64x64 C sub-tile (2M x 2N wave grid)
  const int wm = (wv >> 1) * 64;
  const int wn = (wv & 1) * 64;

  // fragment addressing: region = [128 rows][32 k-elems] (4096 elems, 8KB).
  // 16B chunk at (row, slot) holds global k-chunk slot ^ ((row>>1)&3);
  // lane reads row (base + (lane&15)), k-chunk (lane>>4) -> swizzled slot
  // chE is per-lane constant (frag bases are 16-row aligned, wm mult of 64).
  const int fr = lane & 15;
  const int kq = lane >> 4;
  const int chE = kq ^ ((fr >> 1) & 3);
  const unsigned fA = (unsigned)((wm + fr) * 32 + chE * 8);
  const unsigned fB = (unsigned)((wn + fr) * 32 + chE * 8);

  // staging: LDS linear chunk i = tid + j*256 -> (row=i>>2, slot=i&3);
  // global source chunk = slot ^ ((row>>1)&3) = (i&3)^((i>>3)&3), j-invariant.
  const unsigned c0   = (unsigned)((tid & 3) ^ ((tid >> 3) & 3));
  const unsigned soff = (unsigned)((tid >> 2) * K + c0 * 8);
  const unsigned kx64 = (unsigned)(K << 6);            // 64 rows * K elems
  const unsigned lOff = (unsigned)(wv * 512 + lane * 8);

  const bf16_t* gA = A + (size_t)bm * K;
  const bf16_t* gB = B + (size_t)bn * K;

#define SMA(b, kh) (sm + (((b) << 1) | (kh)) * 4096)
#define SMB(b, kh) (sm + 16384 + (((b) << 1) | (kh)) * 4096)
#define STG(gbase, lbase)                                   \
  do {                                                      \
    g2l16((gbase) + soff,        (lbase) + lOff);           \
    g2l16((gbase) + soff + kx64, (lbase) + lOff + 2048);    \
  } while (0)

  floatx4 acc[4][4];
  floatx4 zero = {0.0f, 0.0f, 0.0f, 0.0f};
#pragma unroll
  for (int i = 0; i < 4; i++)
#pragma unroll
    for (int j = 0; j < 4; j++) acc[i][j] = zero;

  // ---- prologue: stage tile 0 fully into buffer 0 ----
  STG(gA,      SMA(0, 0));
  STG(gB,      SMB(0, 0));
  STG(gA + 32, SMA(0, 1));
  STG(gB + 32, SMB(0, 1));
  __syncthreads();

  int cur = 0;
  for (int t = 0; t < nt; ++t) {
    const int kc = t << 6;
    // issue next tile's staging FIRST -> latency hides under this tile's math
    if (t + 1 < nt) {
      STG(gA + kc + 64, SMA(cur ^ 1, 0));
      STG(gB + kc + 64, SMB(cur ^ 1, 0));
      STG(gA + kc + 96, SMA(cur ^ 1, 1));
      STG(gB + kc + 96, SMB(cur ^ 1, 1));
    }
    const bf16_t* Ac0 = SMA(cur, 0);
    const bf16_t* Ac1 = SMA(cur, 1);
    const bf16_t* Bc0 = SMB(cur, 0);
    const bf16_t* Bc1 = SMB(cur, 1);
    short8 a_[4], b_[4];

    // ----- k-half 0 -----
#pragma unroll
    for (int i = 0; i < 4; i++) a_[i] = *(const short8*)(Ac0 + fA + i * 512);
#pragma unroll
    for (int i = 0; i < 4; i++) b_[i] = *(const short8*)(Bc0 + fB + i * 512);
#pragma unroll
    for (int mi = 0; mi < 4; mi++)
#pragma unroll
      for (int ni = 0; ni < 4; ni++)
        acc[mi][ni] = __builtin_amdgcn_mfma_f32_16x16x32_bf16(a_[mi], b_[ni], acc[mi][ni], 0, 0, 0);
    SB0();   // register-pressure pin (restriction only)

    // ----- k-half 1 -----
#pragma unroll
    for (int i = 0; i < 4; i++) a_[i] = *(const short8*)(Ac1 + fA + i * 512);
#pragma unroll
    for (int i = 0; i < 4; i++) b_[i] = *(const short8*)(Bc1 + fB + i * 512);
#pragma unroll
    for (int mi = 0; mi < 4; mi++)
#pragma unroll
      for (int ni = 0; ni < 4; ni++)
        acc[mi][ni] = __builtin_amdgcn_mfma_f32_16x16x32_bf16(a_[mi], b_[ni], acc[mi][ni], 0, 0, 0);

    // single drain+barrier per K-tile (vmcnt(0) lgkmcnt(0) + s_barrier)
    __syncthreads();
    cur ^= 1;
  }
#undef STG
#undef SMB
#undef SMA

  // ---- epilogue: LDS-staged, full-line stores (R5 pattern, 64x64/wave) ----
  // sm is dead after the final __syncthreads; each wave uses a PRIVATE 16KB
  // region (no further barriers needed).
  {
    const int er = (lane >> 4) * 4;
    const int ec = lane & 15;
    char* wreg = (char*)sm + wv * 16384;   // per-wave private staging
    // 1) deposit 64 rows x 64 cols with bias+scale
#pragma unroll
    for (int nf = 0; nf < 4; nf++) {
      const int lcol = nf * 16 + ec;                 // 0..63
      const float bval = bias ? bias[bn + wn + lcol] : 0.0f;
#pragma unroll
      for (int mh = 0; mh < 4; mh++) {
#pragma unroll
        for (int r = 0; r < 4; r++) {
          float v = (acc[mh][nf][r] + bval) * scale;
          const int row = mh * 16 + er + r;          // 0..63
          if constexpr (sizeof(OutT) == 4) {
            ((float*)wreg)[row * 64 + lcol] = v;
          } else {
            ((bf16_t*)wreg)[row * 64 + lcol] = f2bf(v);
          }
        }
      }
    }
    // 2) read back 16B/lane along rows; store full aligned 128B lines
    const size_t rbase = (size_t)(bm + wm);
    if constexpr (sizeof(OutT) == 4) {
      const float* tf = (const float*)wreg;          // 64 x 256B rows
      float* Cf = (float*)C;
#pragma unroll
      for (int i = 0; i < 16; i++) {
        const int rr = i * 4 + (lane >> 4);
        floatx4 v = *(const floatx4*)(tf + rr * 64 + (lane & 15) * 4);
        *(floatx4*)(Cf + (rbase + rr) * N + bn + wn + (lane & 15) * 4) = v;
      }
    } else {
      const bf16_t* tb = (const bf16_t*)wreg;        // 64 x 128B rows
      bf16_t* Cb = (bf16_t*)C;
#pragma unroll
      for (int i = 0; i < 8; i++) {
        const int rr = i * 8 + (lane >> 3);
        short8 v = *(const short8*)(tb + rr * 64 + (lane & 7) * 8);
        *(short8*)(Cb + (rbase + rr) * N + bn + wn + (lane & 7) * 8) = v;
      }
    }
  }
}

// ---------- row softmax in place, bf16 [16384][2048], one block per row ----------
__global__ __launch_bounds__(256) void softmax_rows(bf16_t* __restrict__ S) {
  const int tid = threadIdx.x;
  bf16_t* row = S + (size_t)blockIdx.x * 2048;
  uint4v raw = *(const uint4v*)(row + tid * 8);
  float x[8];
#pragma unroll
  for (int j = 0; j < 4; j++) {
    unsigned w = raw[j];
    x[2 * j]     = __uint_as_float(w << 16);
    x[2 * j + 1] = __uint_as_float(w & 0xFFFF0000u);
  }
  float m = -1e30f;
#pragma unroll
  for (int j = 0; j < 8; j++) m = fmaxf(m, x[j]);
  for (int o = 32; o > 0; o >>= 1) m = fmaxf(m, __shfl_xor(m, o, 64));
  __shared__ float red[4];
  if ((tid & 63) == 0) red[tid >> 6] = m;
  __syncthreads();
  m = fmaxf(fmaxf(red[0], red[1]), fmaxf(red[2], red[3]));

  float e[8];
  float s = 0.0f;
#pragma unroll
  for (int j = 0; j < 8; j++) { e[j] = __expf(x[j] - m); s += e[j]; }
  for (int o = 32; o > 0; o >>= 1) s += __shfl_xor(s, o, 64);
  __syncthreads();
  if ((tid & 63) == 0) red[tid >> 6] = s;
  __syncthreads();
  s = red[0] + red[1] + red[2] + red[3];
  float inv = 1.0f / s;

  uint4v o4;
#pragma unroll
  for (int j = 0; j < 4; j++) {
    unsigned lo = f2bf(e[2 * j] * inv);
    unsigned hi = f2bf(e[2 * j + 1] * inv);
    o4[j] = lo | (hi << 16);
  }
  *(uint4v*)(row + tid * 8) = o4;
}

// ---------- V [b][2048][1024] -> Vt [b][1024][2048], 64x64 LDS tiles ----------
__global__ __launch_bounds__(256) void transpose64(const bf16_t* __restrict__ V,
                                                   bf16_t* __restrict__ Vt) {
  __shared__ bf16_t t[64][72];   // 72: keep 16B alignment (144B row) + conflict break
  const int tid = threadIdx.x;
  const int e0 = blockIdx.x * 64;
  const int s0 = blockIdx.y * 64;
  const size_t bb = (size_t)blockIdx.z * (2048 * 1024);
  const int r = tid >> 2;
  const int c = (tid & 3) * 16;
  const bf16_t* src = V + bb + (size_t)(s0 + r) * 1024 + e0 + c;
  uint4v v0 = *(const uint4v*)src;
  uint4v v1 = *(const uint4v*)(src + 8);
  *(uint4v*)&t[r][c]     = v0;
  *(uint4v*)&t[r][c + 8] = v1;
  __syncthreads();
  __attribute__((aligned(16))) bf16_t vals[16];
#pragma unroll
  for (int j = 0; j < 16; j++) vals[j] = t[c + j][r];
  bf16_t* dst = Vt + bb + (size_t)(e0 + r) * 2048 + s0 + c;
  *(uint4v*)dst       = *(const uint4v*)vals;
  *(uint4v*)(dst + 8) = *(const uint4v*)(vals + 8);
}

// ---------- launch ----------
extern "C" void kernel_launch(void* const* d_in, const int* in_sizes, int n_in,
                              void* d_out, int out_size, void* d_ws, size_t ws_size,
                              hipStream_t stream) {
  const float* target = (const float*)d_in[0];
  const float* source = (const float*)d_in[1];
  const float* Wq = (const float*)d_in[2];
  const float* bq = (const float*)d_in[3];
  const float* Wk = (const float*)d_in[4];
  const float* bk = (const float*)d_in[5];
  const float* Wv = (const float*)d_in[6];
  const float* bv = (const float*)d_in[7];
  const float* Wo = (const float*)d_in[8];
  const float* bo = (const float*)d_in[9];
  float* out = (float*)d_out;

  // workspace layout (200 MB total), with overlays:
  //   [0,32M)      Q bf16
  //   [32M,64M)    K bf16
  //   [64M,96M)    V^T bf16
  //   [96M,104M)   Wq/Wk/Wv/Wo bf16
  //   [104M,136M)  target bf16  } S bf16 (64M) overlays both after QKV GEMMs
  //   [136M,168M)  source bf16  }
  //   [168M,200M)  V row-major bf16; attn-out overlays after transpose
  char* ws = (char*)d_ws;
  bf16_t* Qb  = (bf16_t*)(ws + 0);
  bf16_t* Kb  = (bf16_t*)(ws + 33554432);
  bf16_t* Vt  = (bf16_t*)(ws + 67108864);
  bf16_t* Wb  = (bf16_t*)(ws + 100663296);
  bf16_t* Tb  = (bf16_t*)(ws + 109051904);
  bf16_t* Sb  = Tb;                          // 67,108,864 B spanning Tb+Srcb
  bf16_t* Srb = (bf16_t*)(ws + 142606336);
  bf16_t* Vb  = (bf16_t*)(ws + 176160768);
  bf16_t* AO  = Vb;

  // 1. converts (fp32 -> bf16); target+source fused in one dispatch
  conv_in<<<dim3(16384, 2), 256, 0, stream>>>(target, source, Tb, Srb);
  conv_w<<<dim3(1024, 4), 256, 0, stream>>>(Wq, Wk, Wv, Wo, Wb);

  // 2. projections: X @ W^T + b   (Q pre-scaled by 1/sqrt(1024))
  gemm128<<<dim3(8, 128, 1), 256, 0, stream>>>(Tb,  Wb,           bq, Qb, 16384, 1024, 1024, 0L, 0L, 0L, 0.03125f);
  gemm128<<<dim3(8, 128, 1), 256, 0, stream>>>(Srb, Wb + 1048576, bk, Kb, 16384, 1024, 1024, 0L, 0L, 0L, 1.0f);
  gemm128<<<dim3(8, 128, 1), 256, 0, stream>>>(Srb, Wb + 2097152, bv, Vb, 16384, 1024, 1024, 0L, 0L, 0L, 1.0f);

  // 3. V -> V^T per batch
  transpose64<<<dim3(16, 32, 8), 256, 0, stream>>>(Vb, Vt);

  // 4. scores S = Qs @ K^T  (per batch)
  gemm128<<<dim3(16, 16, 8), 256, 0, stream>>>(Qb, Kb, (const float*)nullptr, Sb,
      2048, 2048, 1024, (long)2048 * 1024, (long)2048 * 1024, (long)2048 * 2048, 1.0f);

  // 5. softmax rows, in place
  softmax_rows<<<16384, 256, 0, stream>>>(Sb);

  // 6. out = P @ V  == P @ (V^T)^T  (per batch)
  gemm128<<<dim3(8, 16, 8), 256, 0, stream>>>(Sb, Vt, (const float*)nullptr, AO,
      2048, 1024, 2048, (long)2048 * 2048, (long)1024 * 2048, (long)2048 * 1024, 1.0f);

  // 7. final projection: AO @ Wo^T + bo -> fp32 out
  gemm128<<<dim3(8, 128, 1), 256, 0, stream>>>(AO, Wb + 3145728, bo, out,
      16384, 1024, 1024, 0L, 0L, 0L, 1.0f);
}